// Round 10
// baseline (231.324 us; speedup 1.0000x reference)
//
#include <hip/hip_runtime.h>
#include <hip/hip_bf16.h>

// RPEMultiHeadAttention, MI355X (gfx950).
// Math: rel-pos terms (attn2/attn3) are constant along the softmax axis ->
// softmax shift-invariance -> dead. Reference == plain MHA, scale 1/sqrt(192).
// All external I/O is float32; intermediates bf16 (MFMA), f32 accumulate.
//
// v10: BARRIER-FREE flash. K/V fragments read directly from global (L2-hot
// via XCD swizzle; staging LDS + barriers deleted). Block = 256 thr / 64
// q-rows / full k-range per wave; LDS = 9.2 KB wave-local Ps only ->
// 8 blocks/CU (32 waves/CU, was 16). l accumulated via MFMA-with-ones
// (C-layout row-sums, replicated over lanes -> no VALU adds, no shuffle
// reduce). Epilogue Wo fragments from L2-resident WoT. qkv/init unchanged.

#define N_HEAD 8
#define BATCH  8
#define SEQ    1024
#define DMH    512                   // d_model * n_head
#define SC2    0.10411804386480816f  // (1/sqrt(192)) * log2(e)

typedef __hip_bfloat16 bf16;
typedef __bf16 bf16x8 __attribute__((ext_vector_type(8)));
typedef __bf16 bf16x4 __attribute__((ext_vector_type(4)));
typedef float  f32x4  __attribute__((ext_vector_type(4)));

// ---------------------------------------------------------------------------
// Kernel 0: out = bo (bias-init for atomic accumulation) + bf16 transposed
// weights: WqT/WkT/WvT [512 n][64 k] = W[k][n];  WoT [64 c][512 k] = Wo[k][c].
// ---------------------------------------------------------------------------
__global__ __launch_bounds__(256)
void init_kernel(const float* __restrict__ Wq, const float* __restrict__ Wk,
                 const float* __restrict__ Wv, const float* __restrict__ Wo,
                 const float* __restrict__ bo, float* __restrict__ out,
                 bf16* __restrict__ WqT, bf16* __restrict__ WkT,
                 bf16* __restrict__ WvT, bf16* __restrict__ WoT)
{
    const int idx = blockIdx.x * 256 + threadIdx.x;   // grid covers 8192*64
    out[idx] = bo[idx & 63];
    if (idx < 512 * 64) {
        {   // W*T[n*64+k] = W[k*512+n]  (coalesced writes, strided reads, L2)
            const int n = idx >> 6, k = idx & 63;
            WqT[idx] = __float2bfloat16(Wq[(size_t)k * 512 + n]);
            WkT[idx] = __float2bfloat16(Wk[(size_t)k * 512 + n]);
            WvT[idx] = __float2bfloat16(Wv[(size_t)k * 512 + n]);
        }
        {   // WoT[c*512+k] = Wo[k*64+c]
            const int c = idx >> 9, k = idx & 511;
            WoT[idx] = __float2bfloat16(Wo[(size_t)k * 64 + c]);
        }
    }
}

// ---------------------------------------------------------------------------
// Kernel 1: q1/k1/v1 = X @ W + b via MFMA (unchanged from v8/v9). Block =
// 128 rows x 64 cols (one head), 256 threads = 4 waves x {2 row-sets of 16}.
// MFMA 16x16x32 bf16 verified layouts:
//   A: m=lane&15, k=quad*8+j   B: n=lane&15, k=quad*8+j (== W^T row)
//   C/D: col=lane&15, row=quad*4+reg
// ---------------------------------------------------------------------------
__global__ __launch_bounds__(256)
void qkv_mfma_kernel(const float* __restrict__ Xq, const float* __restrict__ Xk,
                     const float* __restrict__ Xv,
                     const bf16* __restrict__ WqT, const bf16* __restrict__ WkT,
                     const bf16* __restrict__ WvT,
                     const float* __restrict__ bq, const float* __restrict__ bk,
                     const float* __restrict__ bv,
                     bf16* __restrict__ Qh, bf16* __restrict__ Kh,
                     bf16* __restrict__ Vt)
{
    const int rt    = blockIdx.x;   // rows rt*128 .. +127 of [8192]
    const int ct    = blockIdx.y;   // head (cols ct*64 .. +63)
    const int which = blockIdx.z;   // 0=q 1=k 2=v

    const float* __restrict__ X    = which == 0 ? Xq  : (which == 1 ? Xk  : Xv);
    const bf16*  __restrict__ WT   = which == 0 ? WqT : (which == 1 ? WkT : WvT);
    const float* __restrict__ bias = which == 0 ? bq  : (which == 1 ? bk  : bv);

    __shared__ __align__(16) bf16 Xs [128 * 72];  // A tiles [m][k] (V: reused as VtS[64][136])
    __shared__ __align__(16) bf16 Wts[64 * 72];   // B tiles [n][k]
    __shared__ float Bs[64];

    const int tid  = threadIdx.x;
    const int w4   = tid >> 6;
    const int lane = tid & 63;
    const int t16  = lane & 15;
    const int quad = lane >> 4;

    if (tid < 64) Bs[tid] = bias[ct * 64 + tid];
    // stage X (f32 -> bf16): 128x64, coalesced float4 reads
    for (int i = tid; i < 2048; i += 256) {
        const int r = i >> 4, c4 = (i & 15) << 2;
        const float4 v = *(const float4*)&X[(size_t)(rt * 128 + r) * 64 + c4];
        bf16 t[4] = {__float2bfloat16(v.x), __float2bfloat16(v.y),
                     __float2bfloat16(v.z), __float2bfloat16(v.w)};
        *(bf16x4*)&Xs[r * 72 + c4] = *(bf16x4*)t;
    }
    // stage W^T slice [ct*64..+63][64], bf16x8 copies
    for (int i = tid; i < 512; i += 256) {
        const int r8 = i >> 3, c8 = (i & 7) << 3;
        *(bf16x8*)&Wts[r8 * 72 + c8] = *(const bf16x8*)&WT[(size_t)(ct * 64 + r8) * 64 + c8];
    }
    __syncthreads();

    // B fragments (shared across both row-sets)
    bf16x8 bf0[4], bf1[4];
#pragma unroll
    for (int nt = 0; nt < 4; nt++) {
        bf0[nt] = *(const bf16x8*)&Wts[(nt * 16 + t16) * 72 + 0  + quad * 8];
        bf1[nt] = *(const bf16x8*)&Wts[(nt * 16 + t16) * 72 + 32 + quad * 8];
    }

    f32x4 acc[2][4];
#pragma unroll
    for (int rs = 0; rs < 2; rs++) {
        const int m = rs * 64 + w4 * 16 + t16;
        const bf16x8 af0 = *(const bf16x8*)&Xs[m * 72 + 0  + quad * 8];
        const bf16x8 af1 = *(const bf16x8*)&Xs[m * 72 + 32 + quad * 8];
#pragma unroll
        for (int nt = 0; nt < 4; nt++) {
            acc[rs][nt] = (f32x4){0.f, 0.f, 0.f, 0.f};
            acc[rs][nt] = __builtin_amdgcn_mfma_f32_16x16x32_bf16(af0, bf0[nt], acc[rs][nt], 0, 0, 0);
            acc[rs][nt] = __builtin_amdgcn_mfma_f32_16x16x32_bf16(af1, bf1[nt], acc[rs][nt], 0, 0, 0);
        }
    }

    const int b     = rt >> 3;
    const int sbase = (rt & 7) * 128;

    if (which < 2) {
        bf16* O = which == 0 ? Qh : Kh;
        const float sc = (which == 0) ? SC2 : 1.0f;   // fold softmax scale into Q
#pragma unroll
        for (int rs = 0; rs < 2; rs++)
#pragma unroll
            for (int rr = 0; rr < 4; rr++) {
                const int s = sbase + rs * 64 + w4 * 16 + quad * 4 + rr;
                bf16* dst = O + (((size_t)b * N_HEAD + ct) * SEQ + s) * 64 + t16;
#pragma unroll
                for (int nt = 0; nt < 4; nt++)
                    dst[nt * 16] = __float2bfloat16((acc[rs][nt][rr] + Bs[nt * 16 + t16]) * sc);
            }
    } else {
        // V: transpose via LDS overlay (Xs dead), then coalesced stores
        __syncthreads();
        bf16* VtS = Xs;   // [64 c][136 r]
#pragma unroll
        for (int rs = 0; rs < 2; rs++)
#pragma unroll
            for (int nt = 0; nt < 4; nt++)
#pragma unroll
                for (int rr = 0; rr < 4; rr++) {
                    const int rloc = rs * 64 + w4 * 16 + quad * 4 + rr;
                    VtS[(nt * 16 + t16) * 136 + rloc] =
                        __float2bfloat16(acc[rs][nt][rr] + Bs[nt * 16 + t16]);
                }
        __syncthreads();
        for (int i = tid; i < 1024; i += 256) {
            const int c = i >> 4, r8 = (i & 15) << 3;
            *(bf16x8*)&Vt[(((size_t)b * N_HEAD + ct) * 64 + c) * SEQ + sbase + r8] =
                *(const bf16x8*)&VtS[c * 136 + r8];
        }
    }
}

// ---------------------------------------------------------------------------
// Kernel 2: BARRIER-FREE flash attention + fused out-proj.
// Grid (bh=64, qt=16): linear id = bh + 64*qt -> XCD = bh%8, all qt-blocks
// of one (b,h) share an XCD L2 (K/V slice 256 KB, L2-resident).
// Block = 256 threads = 4 waves x 16 q-rows; each wave runs all 16 k-tiles.
// K/V/Wo fragments read DIRECTLY from global (L2): per-instr pattern is
// 16 rows x 64 B contiguous -> full 64 B granules. No __syncthreads anywhere.
// l accumulated via MFMA(P, ones): C/D layout row=quad*4+reg matches Of rows,
// replicated over col lanes -> no adds, no shuffle reduction.
// Fragment addresses = staged-version identities:
//   kf: Kp[(kt*64 + nt*16 + t16)*64 + (0|32) + quad*8]
//   vf: Vtp[(nt*16 + t16)*1024 + kt*64 + (0|32) + quad*8]
//   wf: WoT[(nt*16 + t16)*512 + h*64 + (0|32) + quad*8]
// ---------------------------------------------------------------------------
__global__ __launch_bounds__(256, 8)   // force VGPR<=64: 8 blocks/CU target
void flash_attn_kernel(const bf16* __restrict__ Qh, const bf16* __restrict__ Kh,
                       const bf16* __restrict__ Vt, const bf16* __restrict__ WoT,
                       float* __restrict__ out)
{
    const int bhx  = blockIdx.x;    // 0..63
    const int qt   = blockIdx.y;    // 0..15 (64 q-rows each)
    const int b    = bhx >> 3;
    const int h    = bhx & 7;
    const int tid  = threadIdx.x;
    const int w4   = tid >> 6;      // wave 0..3
    const int lane = tid & 63;
    const int t16  = lane & 15;
    const int quad = lane >> 4;

    const size_t bh = (size_t)b * N_HEAD + h;
    const bf16* __restrict__ Qp  = Qh + bh * (SEQ * 64);  // [1024][64], pre-scaled
    const bf16* __restrict__ Kp  = Kh + bh * (SEQ * 64);  // [1024][64]
    const bf16* __restrict__ Vtp = Vt + bh * (64 * SEQ);  // [64][1024]

    __shared__ __align__(16) bf16 Ps[4][16 * 72];   // wave-local C->A round-trip

    // Q fragments: this wave's 16 rows, resident for all k-tiles
    const int qrow = qt * 64 + w4 * 16 + t16;
    const bf16x8 qf0 = *(const bf16x8*)(Qp + (size_t)qrow * 64 + 0  + quad * 8);
    const bf16x8 qf1 = *(const bf16x8*)(Qp + (size_t)qrow * 64 + 32 + quad * 8);

    // ones fragment for the l row-sum MFMA
    bf16 one_s[8];
#pragma unroll
    for (int j = 0; j < 8; j++) one_s[j] = __float2bfloat16(1.0f);
    const bf16x8 ones = *(const bf16x8*)one_s;

    f32x4 Of[4];
    f32x4 Lf = (f32x4){0.f, 0.f, 0.f, 0.f};
#pragma unroll
    for (int nt = 0; nt < 4; nt++) Of[nt] = (f32x4){0.f, 0.f, 0.f, 0.f};

    bf16* Psw = Ps[w4];

    for (int kt = 0; kt < 16; kt++) {
        // ---- S = Q K^T (exp2 domain: Q pre-scaled); kf direct from L2 ----
        f32x4 Sf[4];
#pragma unroll
        for (int nt = 0; nt < 4; nt++) {
            const size_t kb = (size_t)(kt * 64 + nt * 16 + t16) * 64 + quad * 8;
            const bf16x8 kf0 = *(const bf16x8*)&Kp[kb + 0];
            const bf16x8 kf1 = *(const bf16x8*)&Kp[kb + 32];
            Sf[nt] = (f32x4){0.f, 0.f, 0.f, 0.f};
            Sf[nt] = __builtin_amdgcn_mfma_f32_16x16x32_bf16(qf0, kf0, Sf[nt], 0, 0, 0);
            Sf[nt] = __builtin_amdgcn_mfma_f32_16x16x32_bf16(qf1, kf1, Sf[nt], 0, 0, 0);
        }

        // ---- p = exp2(S) (no max: scores bounded) ----
#pragma unroll
        for (int nt = 0; nt < 4; nt++)
#pragma unroll
            for (int rr = 0; rr < 4; rr++)
                Sf[nt][rr] = exp2f(Sf[nt][rr]);

        // ---- P: C-layout -> wave-local LDS -> A-layout ----
#pragma unroll
        for (int nt = 0; nt < 4; nt++)
#pragma unroll
            for (int rr = 0; rr < 4; rr++)
                Psw[(quad * 4 + rr) * 72 + nt * 16 + t16] = __float2bfloat16(Sf[nt][rr]);

        const bf16x8 pf0 = *(const bf16x8*)&Psw[t16 * 72 + 0  + quad * 8];
        const bf16x8 pf1 = *(const bf16x8*)&Psw[t16 * 72 + 32 + quad * 8];

        // ---- l += rowsum(P) via MFMA-with-ones (rows match Of's C-layout) ----
        Lf = __builtin_amdgcn_mfma_f32_16x16x32_bf16(pf0, ones, Lf, 0, 0, 0);
        Lf = __builtin_amdgcn_mfma_f32_16x16x32_bf16(pf1, ones, Lf, 0, 0, 0);

        // ---- O += P V; vf direct from L2 ----
#pragma unroll
        for (int nt = 0; nt < 4; nt++) {
            const size_t vb = (size_t)(nt * 16 + t16) * SEQ + kt * 64 + quad * 8;
            const bf16x8 vf0 = *(const bf16x8*)&Vtp[vb + 0];
            const bf16x8 vf1 = *(const bf16x8*)&Vtp[vb + 32];
            Of[nt] = __builtin_amdgcn_mfma_f32_16x16x32_bf16(pf0, vf0, Of[nt], 0, 0, 0);
            Of[nt] = __builtin_amdgcn_mfma_f32_16x16x32_bf16(pf1, vf1, Of[nt], 0, 0, 0);
        }
    }

    // ---- fused out-proj: R = (O/l) @ Wo_h, atomicAdd into out ----
    float inv_l[4];
#pragma unroll
    for (int rr = 0; rr < 4; rr++) inv_l[rr] = 1.0f / Lf[rr];
#pragma unroll
    for (int nt = 0; nt < 4; nt++)
#pragma unroll
        for (int rr = 0; rr < 4; rr++)
            Psw[(quad * 4 + rr) * 72 + nt * 16 + t16] =
                __float2bfloat16(Of[nt][rr] * inv_l[rr]);

    const bf16x8 pf0 = *(const bf16x8*)&Psw[t16 * 72 + 0  + quad * 8];
    const bf16x8 pf1 = *(const bf16x8*)&Psw[t16 * 72 + 32 + quad * 8];

    f32x4 R[4];
#pragma unroll
    for (int nt = 0; nt < 4; nt++) {
        const size_t wb = (size_t)(nt * 16 + t16) * 512 + h * 64 + quad * 8;
        const bf16x8 wf0 = *(const bf16x8*)&WoT[wb + 0];
        const bf16x8 wf1 = *(const bf16x8*)&WoT[wb + 32];
        R[nt] = (f32x4){0.f, 0.f, 0.f, 0.f};
        R[nt] = __builtin_amdgcn_mfma_f32_16x16x32_bf16(pf0, wf0, R[nt], 0, 0, 0);
        R[nt] = __builtin_amdgcn_mfma_f32_16x16x32_bf16(pf1, wf1, R[nt], 0, 0, 0);
    }

    const int srow_base = qt * 64 + w4 * 16 + quad * 4;
#pragma unroll
    for (int rr = 0; rr < 4; rr++) {
        const size_t base = ((size_t)b * SEQ + srow_base + rr) * 64;
#pragma unroll
        for (int nt = 0; nt < 4; nt++)
            atomicAdd(&out[base + nt * 16 + t16], R[nt][rr]);
    }
}

// ---------------------------------------------------------------------------
extern "C" void kernel_launch(void* const* d_in, const int* in_sizes, int n_in,
                              void* d_out, int out_size, void* d_ws, size_t ws_size,
                              hipStream_t stream)
{
    const float* query = (const float*)d_in[0];
    const float* key_  = (const float*)d_in[1];
    const float* value = (const float*)d_in[2];
    const float* Wq    = (const float*)d_in[3];
    const float* bq    = (const float*)d_in[4];
    const float* Wk    = (const float*)d_in[5];
    const float* bk    = (const float*)d_in[6];
    const float* Wv    = (const float*)d_in[7];
    const float* bv    = (const float*)d_in[8];
    const float* Wo    = (const float*)d_in[9];
    const float* bo    = (const float*)d_in[10];
    // d_in[11..15] dead (softmax shift-invariance)

    float* out = (float*)d_out;
    char* ws   = (char*)d_ws;
    bf16* Qh  = (bf16*)(ws + (size_t) 0 * 1024 * 1024);          // [B,H,S,64]  8 MB
    bf16* Kh  = (bf16*)(ws + (size_t) 8 * 1024 * 1024);          //             8 MB
    bf16* Vt  = (bf16*)(ws + (size_t)16 * 1024 * 1024);          // [B,H,64,S]  8 MB
    bf16* WoT = (bf16*)(ws + (size_t)24 * 1024 * 1024);          // [64,512]   64 KB
    bf16* WqT = (bf16*)(ws + (size_t)24 * 1024 * 1024 + 65536);  // [512,64]   64 KB
    bf16* WkT = (bf16*)(ws + (size_t)24 * 1024 * 1024 + 131072); //            64 KB
    bf16* WvT = (bf16*)(ws + (size_t)24 * 1024 * 1024 + 196608); //            64 KB

    init_kernel<<<dim3(2048), 256, 0, stream>>>(Wq, Wk, Wv, Wo, bo, out,
                                                WqT, WkT, WvT, WoT);
    qkv_mfma_kernel<<<dim3(64, 8, 3), 256, 0, stream>>>(
        query, key_, value, WqT, WkT, WvT, bq, bk, bv, Qh, Kh, Vt);
    flash_attn_kernel<<<dim3(64, 16), 256, 0, stream>>>(Qh, Kh, Vt, WoT, out);
}

// Round 11
// 228.217 us; speedup vs baseline: 1.0136x; 1.0136x over previous
//
#include <hip/hip_runtime.h>
#include <hip/hip_bf16.h>

// RPEMultiHeadAttention, MI355X (gfx950).
// Math: rel-pos terms (attn2/attn3) are constant along the softmax axis ->
// softmax shift-invariance -> dead. Reference == plain MHA, scale 1/sqrt(192).
// All external I/O is float32; intermediates bf16 (MFMA), f32 accumulate.
//
// v11: v10 barrier-free flash with the VGPR strangulation removed.
// v10's __launch_bounds__(256,8) forced VGPR_Count=32 -> zero MLP, fully
// serialized L2 latency (132 us, MfmaUtil 5.8%). Now (256,4): 128-VGPR
// budget, compiler can hold fragments + hoist next-kt kf/vf loads.
// 4 blocks/CU = 16 waves/CU, NO barriers. Everything else unchanged.

#define N_HEAD 8
#define BATCH  8
#define SEQ    1024
#define DMH    512                   // d_model * n_head
#define SC2    0.10411804386480816f  // (1/sqrt(192)) * log2(e)

typedef __hip_bfloat16 bf16;
typedef __bf16 bf16x8 __attribute__((ext_vector_type(8)));
typedef __bf16 bf16x4 __attribute__((ext_vector_type(4)));
typedef float  f32x4  __attribute__((ext_vector_type(4)));

// ---------------------------------------------------------------------------
// Kernel 0: out = bo (bias-init for atomic accumulation) + bf16 transposed
// weights: WqT/WkT/WvT [512 n][64 k] = W[k][n];  WoT [64 c][512 k] = Wo[k][c].
// ---------------------------------------------------------------------------
__global__ __launch_bounds__(256)
void init_kernel(const float* __restrict__ Wq, const float* __restrict__ Wk,
                 const float* __restrict__ Wv, const float* __restrict__ Wo,
                 const float* __restrict__ bo, float* __restrict__ out,
                 bf16* __restrict__ WqT, bf16* __restrict__ WkT,
                 bf16* __restrict__ WvT, bf16* __restrict__ WoT)
{
    const int idx = blockIdx.x * 256 + threadIdx.x;   // grid covers 8192*64
    out[idx] = bo[idx & 63];
    if (idx < 512 * 64) {
        {   // W*T[n*64+k] = W[k*512+n]  (coalesced writes, strided reads, L2)
            const int n = idx >> 6, k = idx & 63;
            WqT[idx] = __float2bfloat16(Wq[(size_t)k * 512 + n]);
            WkT[idx] = __float2bfloat16(Wk[(size_t)k * 512 + n]);
            WvT[idx] = __float2bfloat16(Wv[(size_t)k * 512 + n]);
        }
        {   // WoT[c*512+k] = Wo[k*64+c]
            const int c = idx >> 9, k = idx & 511;
            WoT[idx] = __float2bfloat16(Wo[(size_t)k * 64 + c]);
        }
    }
}

// ---------------------------------------------------------------------------
// Kernel 1: q1/k1/v1 = X @ W + b via MFMA (unchanged from v8/v9). Block =
// 128 rows x 64 cols (one head), 256 threads = 4 waves x {2 row-sets of 16}.
// MFMA 16x16x32 bf16 verified layouts:
//   A: m=lane&15, k=quad*8+j   B: n=lane&15, k=quad*8+j (== W^T row)
//   C/D: col=lane&15, row=quad*4+reg
// ---------------------------------------------------------------------------
__global__ __launch_bounds__(256)
void qkv_mfma_kernel(const float* __restrict__ Xq, const float* __restrict__ Xk,
                     const float* __restrict__ Xv,
                     const bf16* __restrict__ WqT, const bf16* __restrict__ WkT,
                     const bf16* __restrict__ WvT,
                     const float* __restrict__ bq, const float* __restrict__ bk,
                     const float* __restrict__ bv,
                     bf16* __restrict__ Qh, bf16* __restrict__ Kh,
                     bf16* __restrict__ Vt)
{
    const int rt    = blockIdx.x;   // rows rt*128 .. +127 of [8192]
    const int ct    = blockIdx.y;   // head (cols ct*64 .. +63)
    const int which = blockIdx.z;   // 0=q 1=k 2=v

    const float* __restrict__ X    = which == 0 ? Xq  : (which == 1 ? Xk  : Xv);
    const bf16*  __restrict__ WT   = which == 0 ? WqT : (which == 1 ? WkT : WvT);
    const float* __restrict__ bias = which == 0 ? bq  : (which == 1 ? bk  : bv);

    __shared__ __align__(16) bf16 Xs [128 * 72];  // A tiles [m][k] (V: reused as VtS[64][136])
    __shared__ __align__(16) bf16 Wts[64 * 72];   // B tiles [n][k]
    __shared__ float Bs[64];

    const int tid  = threadIdx.x;
    const int w4   = tid >> 6;
    const int lane = tid & 63;
    const int t16  = lane & 15;
    const int quad = lane >> 4;

    if (tid < 64) Bs[tid] = bias[ct * 64 + tid];
    // stage X (f32 -> bf16): 128x64, coalesced float4 reads
    for (int i = tid; i < 2048; i += 256) {
        const int r = i >> 4, c4 = (i & 15) << 2;
        const float4 v = *(const float4*)&X[(size_t)(rt * 128 + r) * 64 + c4];
        bf16 t[4] = {__float2bfloat16(v.x), __float2bfloat16(v.y),
                     __float2bfloat16(v.z), __float2bfloat16(v.w)};
        *(bf16x4*)&Xs[r * 72 + c4] = *(bf16x4*)t;
    }
    // stage W^T slice [ct*64..+63][64], bf16x8 copies
    for (int i = tid; i < 512; i += 256) {
        const int r8 = i >> 3, c8 = (i & 7) << 3;
        *(bf16x8*)&Wts[r8 * 72 + c8] = *(const bf16x8*)&WT[(size_t)(ct * 64 + r8) * 64 + c8];
    }
    __syncthreads();

    // B fragments (shared across both row-sets)
    bf16x8 bf0[4], bf1[4];
#pragma unroll
    for (int nt = 0; nt < 4; nt++) {
        bf0[nt] = *(const bf16x8*)&Wts[(nt * 16 + t16) * 72 + 0  + quad * 8];
        bf1[nt] = *(const bf16x8*)&Wts[(nt * 16 + t16) * 72 + 32 + quad * 8];
    }

    f32x4 acc[2][4];
#pragma unroll
    for (int rs = 0; rs < 2; rs++) {
        const int m = rs * 64 + w4 * 16 + t16;
        const bf16x8 af0 = *(const bf16x8*)&Xs[m * 72 + 0  + quad * 8];
        const bf16x8 af1 = *(const bf16x8*)&Xs[m * 72 + 32 + quad * 8];
#pragma unroll
        for (int nt = 0; nt < 4; nt++) {
            acc[rs][nt] = (f32x4){0.f, 0.f, 0.f, 0.f};
            acc[rs][nt] = __builtin_amdgcn_mfma_f32_16x16x32_bf16(af0, bf0[nt], acc[rs][nt], 0, 0, 0);
            acc[rs][nt] = __builtin_amdgcn_mfma_f32_16x16x32_bf16(af1, bf1[nt], acc[rs][nt], 0, 0, 0);
        }
    }

    const int b     = rt >> 3;
    const int sbase = (rt & 7) * 128;

    if (which < 2) {
        bf16* O = which == 0 ? Qh : Kh;
        const float sc = (which == 0) ? SC2 : 1.0f;   // fold softmax scale into Q
#pragma unroll
        for (int rs = 0; rs < 2; rs++)
#pragma unroll
            for (int rr = 0; rr < 4; rr++) {
                const int s = sbase + rs * 64 + w4 * 16 + quad * 4 + rr;
                bf16* dst = O + (((size_t)b * N_HEAD + ct) * SEQ + s) * 64 + t16;
#pragma unroll
                for (int nt = 0; nt < 4; nt++)
                    dst[nt * 16] = __float2bfloat16((acc[rs][nt][rr] + Bs[nt * 16 + t16]) * sc);
            }
    } else {
        // V: transpose via LDS overlay (Xs dead), then coalesced stores
        __syncthreads();
        bf16* VtS = Xs;   // [64 c][136 r]
#pragma unroll
        for (int rs = 0; rs < 2; rs++)
#pragma unroll
            for (int nt = 0; nt < 4; nt++)
#pragma unroll
                for (int rr = 0; rr < 4; rr++) {
                    const int rloc = rs * 64 + w4 * 16 + quad * 4 + rr;
                    VtS[(nt * 16 + t16) * 136 + rloc] =
                        __float2bfloat16(acc[rs][nt][rr] + Bs[nt * 16 + t16]);
                }
        __syncthreads();
        for (int i = tid; i < 1024; i += 256) {
            const int c = i >> 4, r8 = (i & 15) << 3;
            *(bf16x8*)&Vt[(((size_t)b * N_HEAD + ct) * 64 + c) * SEQ + sbase + r8] =
                *(const bf16x8*)&VtS[c * 136 + r8];
        }
    }
}

// ---------------------------------------------------------------------------
// Kernel 2: BARRIER-FREE flash attention + fused out-proj.
// Grid (bh=64, qt=16): linear id = bh + 64*qt -> XCD = bh%8, all qt-blocks
// of one (b,h) share an XCD L2 (K/V slice 256 KB, L2-resident; FETCH 12.3 MB
// measured r10 confirms). Block = 256 threads = 4 waves x 16 q-rows; each
// wave runs all 16 k-tiles. K/V/Wo fragments read DIRECTLY from global (L2).
// No __syncthreads anywhere. l via MFMA(P, ones) (C-layout rows match Of).
//   kf: Kp[(kt*64 + nt*16 + t16)*64 + (0|32) + quad*8]
//   vf: Vtp[(nt*16 + t16)*1024 + kt*64 + (0|32) + quad*8]
//   wf: WoT[(nt*16 + t16)*512 + h*64 + (0|32) + quad*8]
// launch_bounds (256,4): 128-VGPR budget -- v10's (256,8) forced 32 VGPRs
// and serialized all L2 latency (132 us). 4 blocks/CU = 16 waves/CU.
// ---------------------------------------------------------------------------
__global__ __launch_bounds__(256, 4)
void flash_attn_kernel(const bf16* __restrict__ Qh, const bf16* __restrict__ Kh,
                       const bf16* __restrict__ Vt, const bf16* __restrict__ WoT,
                       float* __restrict__ out)
{
    const int bhx  = blockIdx.x;    // 0..63
    const int qt   = blockIdx.y;    // 0..15 (64 q-rows each)
    const int b    = bhx >> 3;
    const int h    = bhx & 7;
    const int tid  = threadIdx.x;
    const int w4   = tid >> 6;      // wave 0..3
    const int lane = tid & 63;
    const int t16  = lane & 15;
    const int quad = lane >> 4;

    const size_t bh = (size_t)b * N_HEAD + h;
    const bf16* __restrict__ Qp  = Qh + bh * (SEQ * 64);  // [1024][64], pre-scaled
    const bf16* __restrict__ Kp  = Kh + bh * (SEQ * 64);  // [1024][64]
    const bf16* __restrict__ Vtp = Vt + bh * (64 * SEQ);  // [64][1024]

    __shared__ __align__(16) bf16 Ps[4][16 * 72];   // wave-local C->A round-trip

    // Q fragments: this wave's 16 rows, resident for all k-tiles
    const int qrow = qt * 64 + w4 * 16 + t16;
    const bf16x8 qf0 = *(const bf16x8*)(Qp + (size_t)qrow * 64 + 0  + quad * 8);
    const bf16x8 qf1 = *(const bf16x8*)(Qp + (size_t)qrow * 64 + 32 + quad * 8);

    // ones fragment for the l row-sum MFMA
    bf16 one_s[8];
#pragma unroll
    for (int j = 0; j < 8; j++) one_s[j] = __float2bfloat16(1.0f);
    const bf16x8 ones = *(const bf16x8*)one_s;

    f32x4 Of[4];
    f32x4 Lf = (f32x4){0.f, 0.f, 0.f, 0.f};
#pragma unroll
    for (int nt = 0; nt < 4; nt++) Of[nt] = (f32x4){0.f, 0.f, 0.f, 0.f};

    bf16* Psw = Ps[w4];

    for (int kt = 0; kt < 16; kt++) {
        // ---- S = Q K^T (exp2 domain: Q pre-scaled); kf direct from L2 ----
        f32x4 Sf[4];
#pragma unroll
        for (int nt = 0; nt < 4; nt++) {
            const size_t kb = (size_t)(kt * 64 + nt * 16 + t16) * 64 + quad * 8;
            const bf16x8 kf0 = *(const bf16x8*)&Kp[kb + 0];
            const bf16x8 kf1 = *(const bf16x8*)&Kp[kb + 32];
            Sf[nt] = (f32x4){0.f, 0.f, 0.f, 0.f};
            Sf[nt] = __builtin_amdgcn_mfma_f32_16x16x32_bf16(qf0, kf0, Sf[nt], 0, 0, 0);
            Sf[nt] = __builtin_amdgcn_mfma_f32_16x16x32_bf16(qf1, kf1, Sf[nt], 0, 0, 0);
        }

        // ---- p = exp2(S) (no max: scores bounded) ----
#pragma unroll
        for (int nt = 0; nt < 4; nt++)
#pragma unroll
            for (int rr = 0; rr < 4; rr++)
                Sf[nt][rr] = exp2f(Sf[nt][rr]);

        // ---- P: C-layout -> wave-local LDS -> A-layout ----
#pragma unroll
        for (int nt = 0; nt < 4; nt++)
#pragma unroll
            for (int rr = 0; rr < 4; rr++)
                Psw[(quad * 4 + rr) * 72 + nt * 16 + t16] = __float2bfloat16(Sf[nt][rr]);

        const bf16x8 pf0 = *(const bf16x8*)&Psw[t16 * 72 + 0  + quad * 8];
        const bf16x8 pf1 = *(const bf16x8*)&Psw[t16 * 72 + 32 + quad * 8];

        // ---- l += rowsum(P) via MFMA-with-ones (rows match Of's C-layout) ----
        Lf = __builtin_amdgcn_mfma_f32_16x16x32_bf16(pf0, ones, Lf, 0, 0, 0);
        Lf = __builtin_amdgcn_mfma_f32_16x16x32_bf16(pf1, ones, Lf, 0, 0, 0);

        // ---- O += P V; vf direct from L2 ----
#pragma unroll
        for (int nt = 0; nt < 4; nt++) {
            const size_t vb = (size_t)(nt * 16 + t16) * SEQ + kt * 64 + quad * 8;
            const bf16x8 vf0 = *(const bf16x8*)&Vtp[vb + 0];
            const bf16x8 vf1 = *(const bf16x8*)&Vtp[vb + 32];
            Of[nt] = __builtin_amdgcn_mfma_f32_16x16x32_bf16(pf0, vf0, Of[nt], 0, 0, 0);
            Of[nt] = __builtin_amdgcn_mfma_f32_16x16x32_bf16(pf1, vf1, Of[nt], 0, 0, 0);
        }
    }

    // ---- fused out-proj: R = (O/l) @ Wo_h, atomicAdd into out ----
    float inv_l[4];
#pragma unroll
    for (int rr = 0; rr < 4; rr++) inv_l[rr] = 1.0f / Lf[rr];
#pragma unroll
    for (int nt = 0; nt < 4; nt++)
#pragma unroll
        for (int rr = 0; rr < 4; rr++)
            Psw[(quad * 4 + rr) * 72 + nt * 16 + t16] =
                __float2bfloat16(Of[nt][rr] * inv_l[rr]);

    const bf16x8 pf0 = *(const bf16x8*)&Psw[t16 * 72 + 0  + quad * 8];
    const bf16x8 pf1 = *(const bf16x8*)&Psw[t16 * 72 + 32 + quad * 8];

    f32x4 R[4];
#pragma unroll
    for (int nt = 0; nt < 4; nt++) {
        const size_t wb = (size_t)(nt * 16 + t16) * 512 + h * 64 + quad * 8;
        const bf16x8 wf0 = *(const bf16x8*)&WoT[wb + 0];
        const bf16x8 wf1 = *(const bf16x8*)&WoT[wb + 32];
        R[nt] = (f32x4){0.f, 0.f, 0.f, 0.f};
        R[nt] = __builtin_amdgcn_mfma_f32_16x16x32_bf16(pf0, wf0, R[nt], 0, 0, 0);
        R[nt] = __builtin_amdgcn_mfma_f32_16x16x32_bf16(pf1, wf1, R[nt], 0, 0, 0);
    }

    const int srow_base = qt * 64 + w4 * 16 + quad * 4;
#pragma unroll
    for (int rr = 0; rr < 4; rr++) {
        const size_t base = ((size_t)b * SEQ + srow_base + rr) * 64;
#pragma unroll
        for (int nt = 0; nt < 4; nt++)
            atomicAdd(&out[base + nt * 16 + t16], R[nt][rr]);
    }
}

// ---------------------------------------------------------------------------
extern "C" void kernel_launch(void* const* d_in, const int* in_sizes, int n_in,
                              void* d_out, int out_size, void* d_ws, size_t ws_size,
                              hipStream_t stream)
{
    const float* query = (const float*)d_in[0];
    const float* key_  = (const float*)d_in[1];
    const float* value = (const float*)d_in[2];
    const float* Wq    = (const float*)d_in[3];
    const float* bq    = (const float*)d_in[4];
    const float* Wk    = (const float*)d_in[5];
    const float* bk    = (const float*)d_in[6];
    const float* Wv    = (const float*)d_in[7];
    const float* bv    = (const float*)d_in[8];
    const float* Wo    = (const float*)d_in[9];
    const float* bo    = (const float*)d_in[10];
    // d_in[11..15] dead (softmax shift-invariance)

    float* out = (float*)d_out;
    char* ws   = (char*)d_ws;
    bf16* Qh  = (bf16*)(ws + (size_t) 0 * 1024 * 1024);          // [B,H,S,64]  8 MB
    bf16* Kh  = (bf16*)(ws + (size_t) 8 * 1024 * 1024);          //             8 MB
    bf16* Vt  = (bf16*)(ws + (size_t)16 * 1024 * 1024);          // [B,H,64,S]  8 MB
    bf16* WoT = (bf16*)(ws + (size_t)24 * 1024 * 1024);          // [64,512]   64 KB
    bf16* WqT = (bf16*)(ws + (size_t)24 * 1024 * 1024 + 65536);  // [512,64]   64 KB
    bf16* WkT = (bf16*)(ws + (size_t)24 * 1024 * 1024 + 131072); //            64 KB
    bf16* WvT = (bf16*)(ws + (size_t)24 * 1024 * 1024 + 196608); //            64 KB

    init_kernel<<<dim3(2048), 256, 0, stream>>>(Wq, Wk, Wv, Wo, bo, out,
                                                WqT, WkT, WvT, WoT);
    qkv_mfma_kernel<<<dim3(64, 8, 3), 256, 0, stream>>>(
        query, key_, value, WqT, WkT, WvT, bq, bk, bv, Qh, Kh, Vt);
    flash_attn_kernel<<<dim3(64, 16), 256, 0, stream>>>(Qh, Kh, Vt, WoT, out);
}

// Round 12
// 140.725 us; speedup vs baseline: 1.6438x; 1.6217x over previous
//
#include <hip/hip_runtime.h>
#include <hip/hip_bf16.h>

// RPEMultiHeadAttention, MI355X (gfx950).
// Math: rel-pos terms (attn2/attn3) are constant along the softmax axis ->
// softmax shift-invariance -> dead. Reference == plain MHA, scale 1/sqrt(192).
// All external I/O is float32; intermediates bf16 (MFMA), f32 accumulate.
//
// v12 = v9 (best measured: 141.45 us) + coalesced-read init transposes.
// v10/v11 barrier-free direction falsified: compiler won't hold L2 loads in
// regs (VGPR=40 despite 128 budget), and per-wave K/V refetch puts ~1.07 GB
// through L2 (floor ~31 us) vs ~134 MB staged. Staged v9 flash = 46.4 us.

#define N_HEAD 8
#define BATCH  8
#define SEQ    1024
#define DMH    512                   // d_model * n_head
#define SC2    0.10411804386480816f  // (1/sqrt(192)) * log2(e)

typedef __hip_bfloat16 bf16;
typedef __bf16 bf16x8 __attribute__((ext_vector_type(8)));
typedef __bf16 bf16x4 __attribute__((ext_vector_type(4)));
typedef float  f32x4  __attribute__((ext_vector_type(4)));

// ---------------------------------------------------------------------------
// Kernel 0: out = bo (bias-init for atomic accumulation) + bf16 transposed
// weights: WqT/WkT/WvT [512 n][64 k] = W[k][n];  WoT [64 c][512 k] = Wo[k][c].
// All W reads coalesced; transposed writes strided (stores don't stall).
// ---------------------------------------------------------------------------
__global__ __launch_bounds__(256)
void init_kernel(const float* __restrict__ Wq, const float* __restrict__ Wk,
                 const float* __restrict__ Wv, const float* __restrict__ Wo,
                 const float* __restrict__ bo, float* __restrict__ out,
                 bf16* __restrict__ WqT, bf16* __restrict__ WkT,
                 bf16* __restrict__ WvT, bf16* __restrict__ WoT)
{
    const int idx = blockIdx.x * 256 + threadIdx.x;   // grid covers 8192*64
    out[idx] = bo[idx & 63];
    if (idx < 512 * 64) {
        {   // W*T[n*64+k] = W[k*512+n]: read W*[idx] coalesced, write strided
            const int k = idx >> 9, n = idx & 511;
            WqT[(size_t)n * 64 + k] = __float2bfloat16(Wq[idx]);
            WkT[(size_t)n * 64 + k] = __float2bfloat16(Wk[idx]);
            WvT[(size_t)n * 64 + k] = __float2bfloat16(Wv[idx]);
        }
        {   // WoT[c*512+k] = Wo[k*64+c]: read Wo[idx] coalesced, write strided
            const int k = idx >> 6, c = idx & 63;
            WoT[(size_t)c * 512 + k] = __float2bfloat16(Wo[idx]);
        }
    }
}

// ---------------------------------------------------------------------------
// Kernel 1: q1/k1/v1 = X @ W + b via MFMA. Block = 128 rows x 64 cols (one
// head), 256 threads = 4 waves x {2 row-sets of 16}. Grid (rt,ct,which):
// linear id = rt + 64*ct + 512*which -> XCD = rt%8, so the 8 head-blocks of
// one rt share an XCD L2 (X tile fetched once).
// MFMA 16x16x32 bf16 verified layouts:
//   A: m=lane&15, k=quad*8+j   B: n=lane&15, k=quad*8+j (== W^T row)
//   C/D: col=lane&15, row=quad*4+reg
// ---------------------------------------------------------------------------
__global__ __launch_bounds__(256)
void qkv_mfma_kernel(const float* __restrict__ Xq, const float* __restrict__ Xk,
                     const float* __restrict__ Xv,
                     const bf16* __restrict__ WqT, const bf16* __restrict__ WkT,
                     const bf16* __restrict__ WvT,
                     const float* __restrict__ bq, const float* __restrict__ bk,
                     const float* __restrict__ bv,
                     bf16* __restrict__ Qh, bf16* __restrict__ Kh,
                     bf16* __restrict__ Vt)
{
    const int rt    = blockIdx.x;   // rows rt*128 .. +127 of [8192]
    const int ct    = blockIdx.y;   // head (cols ct*64 .. +63)
    const int which = blockIdx.z;   // 0=q 1=k 2=v

    const float* __restrict__ X    = which == 0 ? Xq  : (which == 1 ? Xk  : Xv);
    const bf16*  __restrict__ WT   = which == 0 ? WqT : (which == 1 ? WkT : WvT);
    const float* __restrict__ bias = which == 0 ? bq  : (which == 1 ? bk  : bv);

    __shared__ __align__(16) bf16 Xs [128 * 72];  // A tiles [m][k] (V: reused as VtS[64][136])
    __shared__ __align__(16) bf16 Wts[64 * 72];   // B tiles [n][k]
    __shared__ float Bs[64];

    const int tid  = threadIdx.x;
    const int w4   = tid >> 6;
    const int lane = tid & 63;
    const int t16  = lane & 15;
    const int quad = lane >> 4;

    if (tid < 64) Bs[tid] = bias[ct * 64 + tid];
    // stage X (f32 -> bf16): 128x64, coalesced float4 reads
    for (int i = tid; i < 2048; i += 256) {
        const int r = i >> 4, c4 = (i & 15) << 2;
        const float4 v = *(const float4*)&X[(size_t)(rt * 128 + r) * 64 + c4];
        bf16 t[4] = {__float2bfloat16(v.x), __float2bfloat16(v.y),
                     __float2bfloat16(v.z), __float2bfloat16(v.w)};
        *(bf16x4*)&Xs[r * 72 + c4] = *(bf16x4*)t;
    }
    // stage W^T slice [ct*64..+63][64], bf16x8 copies
    for (int i = tid; i < 512; i += 256) {
        const int r8 = i >> 3, c8 = (i & 7) << 3;
        *(bf16x8*)&Wts[r8 * 72 + c8] = *(const bf16x8*)&WT[(size_t)(ct * 64 + r8) * 64 + c8];
    }
    __syncthreads();

    // B fragments (shared across both row-sets)
    bf16x8 bf0[4], bf1[4];
#pragma unroll
    for (int nt = 0; nt < 4; nt++) {
        bf0[nt] = *(const bf16x8*)&Wts[(nt * 16 + t16) * 72 + 0  + quad * 8];
        bf1[nt] = *(const bf16x8*)&Wts[(nt * 16 + t16) * 72 + 32 + quad * 8];
    }

    f32x4 acc[2][4];
#pragma unroll
    for (int rs = 0; rs < 2; rs++) {
        const int m = rs * 64 + w4 * 16 + t16;
        const bf16x8 af0 = *(const bf16x8*)&Xs[m * 72 + 0  + quad * 8];
        const bf16x8 af1 = *(const bf16x8*)&Xs[m * 72 + 32 + quad * 8];
#pragma unroll
        for (int nt = 0; nt < 4; nt++) {
            acc[rs][nt] = (f32x4){0.f, 0.f, 0.f, 0.f};
            acc[rs][nt] = __builtin_amdgcn_mfma_f32_16x16x32_bf16(af0, bf0[nt], acc[rs][nt], 0, 0, 0);
            acc[rs][nt] = __builtin_amdgcn_mfma_f32_16x16x32_bf16(af1, bf1[nt], acc[rs][nt], 0, 0, 0);
        }
    }

    const int b     = rt >> 3;
    const int sbase = (rt & 7) * 128;

    if (which < 2) {
        bf16* O = which == 0 ? Qh : Kh;
        const float sc = (which == 0) ? SC2 : 1.0f;   // fold softmax scale into Q
#pragma unroll
        for (int rs = 0; rs < 2; rs++)
#pragma unroll
            for (int rr = 0; rr < 4; rr++) {
                const int s = sbase + rs * 64 + w4 * 16 + quad * 4 + rr;
                bf16* dst = O + (((size_t)b * N_HEAD + ct) * SEQ + s) * 64 + t16;
#pragma unroll
                for (int nt = 0; nt < 4; nt++)
                    dst[nt * 16] = __float2bfloat16((acc[rs][nt][rr] + Bs[nt * 16 + t16]) * sc);
            }
    } else {
        // V: transpose via LDS overlay (Xs dead), then coalesced stores
        __syncthreads();
        bf16* VtS = Xs;   // [64 c][136 r]
#pragma unroll
        for (int rs = 0; rs < 2; rs++)
#pragma unroll
            for (int nt = 0; nt < 4; nt++)
#pragma unroll
                for (int rr = 0; rr < 4; rr++) {
                    const int rloc = rs * 64 + w4 * 16 + quad * 4 + rr;
                    VtS[(nt * 16 + t16) * 136 + rloc] =
                        __float2bfloat16(acc[rs][nt][rr] + Bs[nt * 16 + t16]);
                }
        __syncthreads();
        for (int i = tid; i < 1024; i += 256) {
            const int c = i >> 4, r8 = (i & 15) << 3;
            *(bf16x8*)&Vt[(((size_t)b * N_HEAD + ct) * 64 + c) * SEQ + sbase + r8] =
                *(const bf16x8*)&VtS[c * 136 + r8];
        }
    }
}

// ---------------------------------------------------------------------------
// Kernel 2: flash attention + fused out-proj (v9: best measured, 46.4 us).
// Grid (bh=64, qt=8): linear id = bh + 64*qt -> XCD = bh%8, all qt-blocks of
// one (b,h) share an XCD L2. Block = 512 threads = {4 waves x 2 k-halves} x
// 2 row-sets of 16. Register-prefetch staging; phase-structured inner loop
// (K/V fragments read once, used by both row-sets). Padded epilogue exchange.
// ---------------------------------------------------------------------------
__global__ __launch_bounds__(512, 4)
void flash_attn_kernel(const bf16* __restrict__ Qh, const bf16* __restrict__ Kh,
                       const bf16* __restrict__ Vt, const bf16* __restrict__ WoT,
                       float* __restrict__ out)
{
    const int bhx  = blockIdx.x;    // 0..63
    const int qt   = blockIdx.y;    // 0..7 (128 q-rows each)
    const int b    = bhx >> 3;
    const int h    = bhx & 7;
    const int tid  = threadIdx.x;
    const int wave = tid >> 6;      // 0..7
    const int w4   = wave & 3;
    const int kh   = wave >> 2;     // k-half: 0 -> kt 0..7, 1 -> kt 8..15
    const int lane = tid & 63;
    const int t16  = lane & 15;
    const int quad = lane >> 4;

    const size_t bh = (size_t)b * N_HEAD + h;
    const bf16* __restrict__ Qp  = Qh + bh * (SEQ * 64);  // [1024][64], pre-scaled
    const bf16* __restrict__ Kp  = Kh + bh * (SEQ * 64);  // [1024][64]
    const bf16* __restrict__ Vtp = Vt + bh * (64 * SEQ);  // [64][1024]

    __shared__ __align__(16) bf16 smem[36864];            // 72 KB
    bf16* KsB  = smem;                // [2][64*72]
    bf16* VtsB = smem + 9216;         // [2][64*72]
    bf16* PsB  = smem + 18432;        // [2][8][16*72]

    bf16x8 qf0[2], qf1[2];
#pragma unroll
    for (int rs = 0; rs < 2; rs++) {
        const int qrow = qt * 128 + rs * 64 + w4 * 16 + t16;
        qf0[rs] = *(const bf16x8*)(Qp + (size_t)qrow * 64 + 0  + quad * 8);
        qf1[rs] = *(const bf16x8*)(Qp + (size_t)qrow * 64 + 32 + quad * 8);
    }

    f32x4 Of[2][4];
    float l_i[2][4];
#pragma unroll
    for (int rs = 0; rs < 2; rs++) {
#pragma unroll
        for (int nt = 0; nt < 4; nt++) Of[rs][nt] = (f32x4){0.f, 0.f, 0.f, 0.f};
#pragma unroll
        for (int rr = 0; rr < 4; rr++) l_i[rs][rr] = 0.f;
    }

    // ---- register-prefetch staging: each thread owns 4 fixed 16B chunks ----
    const int r8s = tid >> 3;            // 0..63
    const int c8s = (tid & 7) << 3;      // 0..56
    bf16x8 pre[4];
#define LOAD_TILES(kt_)                                                          \
    do {                                                                         \
        pre[0] = *(const bf16x8*)&Kp [(size_t)((kt_) * 64 + r8s) * 64 + c8s];    \
        pre[1] = *(const bf16x8*)&Vtp[(size_t)r8s * SEQ + (kt_) * 64 + c8s];     \
        pre[2] = *(const bf16x8*)&Kp [(size_t)(512 + (kt_) * 64 + r8s) * 64 + c8s]; \
        pre[3] = *(const bf16x8*)&Vtp[(size_t)r8s * SEQ + 512 + (kt_) * 64 + c8s];  \
    } while (0)

    LOAD_TILES(0);

    for (int kt = 0; kt < 8; kt++) {
        *(bf16x8*)&KsB [       r8s * 72 + c8s] = pre[0];
        *(bf16x8*)&VtsB[       r8s * 72 + c8s] = pre[1];
        *(bf16x8*)&KsB [4608 + r8s * 72 + c8s] = pre[2];
        *(bf16x8*)&VtsB[4608 + r8s * 72 + c8s] = pre[3];
        __syncthreads();

        if (kt < 7) LOAD_TILES(kt + 1);   // latency hidden behind compute below

        const bf16* Ksw  = KsB  + kh * 4608;
        const bf16* Vtsw = VtsB + kh * 4608;

        // ---- Phase A: S = Q K^T, K fragments read ONCE, both row-sets ----
        f32x4 Sf[2][4];
#pragma unroll
        for (int nt = 0; nt < 4; nt++) {
            const bf16x8 kf0 = *(const bf16x8*)&Ksw[(nt * 16 + t16) * 72 + 0  + quad * 8];
            const bf16x8 kf1 = *(const bf16x8*)&Ksw[(nt * 16 + t16) * 72 + 32 + quad * 8];
#pragma unroll
            for (int rs = 0; rs < 2; rs++) {
                Sf[rs][nt] = (f32x4){0.f, 0.f, 0.f, 0.f};
                Sf[rs][nt] = __builtin_amdgcn_mfma_f32_16x16x32_bf16(qf0[rs], kf0, Sf[rs][nt], 0, 0, 0);
                Sf[rs][nt] = __builtin_amdgcn_mfma_f32_16x16x32_bf16(qf1[rs], kf1, Sf[rs][nt], 0, 0, 0);
            }
        }

        // ---- Phase B: p = exp2(S) (no max: scores bounded), Ps round-trip ----
        bf16x8 pf0[2], pf1[2];
#pragma unroll
        for (int rs = 0; rs < 2; rs++) {
#pragma unroll
            for (int nt = 0; nt < 4; nt++)
#pragma unroll
                for (int rr = 0; rr < 4; rr++) {
                    const float p = exp2f(Sf[rs][nt][rr]);
                    Sf[rs][nt][rr] = p;
                    l_i[rs][rr] += p;
                }
            bf16* Psw = PsB + (rs * 8 + wave) * 1152;
#pragma unroll
            for (int nt = 0; nt < 4; nt++)
#pragma unroll
                for (int rr = 0; rr < 4; rr++)
                    Psw[(quad * 4 + rr) * 72 + nt * 16 + t16] =
                        __float2bfloat16(Sf[rs][nt][rr]);
            pf0[rs] = *(const bf16x8*)&Psw[t16 * 72 + 0  + quad * 8];
            pf1[rs] = *(const bf16x8*)&Psw[t16 * 72 + 32 + quad * 8];
        }

        // ---- Phase C: O += P V, V fragments read ONCE, both row-sets ----
#pragma unroll
        for (int nt = 0; nt < 4; nt++) {
            const bf16x8 vf0 = *(const bf16x8*)&Vtsw[(nt * 16 + t16) * 72 + 0  + quad * 8];
            const bf16x8 vf1 = *(const bf16x8*)&Vtsw[(nt * 16 + t16) * 72 + 32 + quad * 8];
#pragma unroll
            for (int rs = 0; rs < 2; rs++) {
                Of[rs][nt] = __builtin_amdgcn_mfma_f32_16x16x32_bf16(pf0[rs], vf0, Of[rs][nt], 0, 0, 0);
                Of[rs][nt] = __builtin_amdgcn_mfma_f32_16x16x32_bf16(pf1[rs], vf1, Of[rs][nt], 0, 0, 0);
            }
        }
        __syncthreads();
    }
#undef LOAD_TILES

    // ---- combine the two k-halves (linear: no-max softmax) ----
    // Epilogue overlay map (bytes from smem base, all 16B-aligned):
    //   Xch f32 [8 row][64 lane] stride 17 dw : [0, 34816)
    //   Lch f32 [8 row][64 lane] stride 5 dw  : [34816, 45056)
    //   WoS bf16 [64][72]                     : [45056, 54272)
    //   Pe  bf16 [4 w4][16*72]                : [54272, 63488)
    float* Xch = (float*)smem;              // stride 17 dwords (conflict-free)
    float* Lch = (float*)(smem + 17408);    // stride 5 dwords
    bf16*  WoS = smem + 22528;
    bf16*  Pe  = smem + 27136;

    if (kh == 1) {
#pragma unroll
        for (int rs = 0; rs < 2; rs++) {
#pragma unroll
            for (int nt = 0; nt < 4; nt++)
#pragma unroll
                for (int rr = 0; rr < 4; rr++)
                    Xch[((w4 * 2 + rs) * 64 + lane) * 17 + nt * 4 + rr] = Of[rs][nt][rr];
#pragma unroll
            for (int rr = 0; rr < 4; rr++)
                Lch[((w4 * 2 + rs) * 64 + lane) * 5 + rr] = l_i[rs][rr];
        }
    }
    {
        const int r8 = tid >> 3, c8 = (tid & 7) << 3;
        *(bf16x8*)&WoS[r8 * 72 + c8] = *(const bf16x8*)&WoT[(size_t)r8 * 512 + h * 64 + c8];
    }
    __syncthreads();

    if (kh == 0) {
#pragma unroll
        for (int rs = 0; rs < 2; rs++) {
#pragma unroll
            for (int nt = 0; nt < 4; nt++)
#pragma unroll
                for (int rr = 0; rr < 4; rr++)
                    Of[rs][nt][rr] += Xch[((w4 * 2 + rs) * 64 + lane) * 17 + nt * 4 + rr];
#pragma unroll
            for (int rr = 0; rr < 4; rr++)
                l_i[rs][rr] += Lch[((w4 * 2 + rs) * 64 + lane) * 5 + rr];
        }

#pragma unroll
        for (int rs = 0; rs < 2; rs++)
#pragma unroll
            for (int off = 8; off >= 1; off >>= 1)
#pragma unroll
                for (int rr = 0; rr < 4; rr++)
                    l_i[rs][rr] += __shfl_xor(l_i[rs][rr], off, 64);

        bf16* Pew = Pe + w4 * 1152;
#pragma unroll
        for (int rs = 0; rs < 2; rs++) {
            float inv_l[4];
#pragma unroll
            for (int rr = 0; rr < 4; rr++) inv_l[rr] = 1.0f / l_i[rs][rr];
#pragma unroll
            for (int nt = 0; nt < 4; nt++)
#pragma unroll
                for (int rr = 0; rr < 4; rr++)
                    Pew[(quad * 4 + rr) * 72 + nt * 16 + t16] =
                        __float2bfloat16(Of[rs][nt][rr] * inv_l[rr]);

            const bf16x8 pf0 = *(const bf16x8*)&Pew[t16 * 72 + 0  + quad * 8];
            const bf16x8 pf1 = *(const bf16x8*)&Pew[t16 * 72 + 32 + quad * 8];

            f32x4 R[4];
#pragma unroll
            for (int nt = 0; nt < 4; nt++) {
                R[nt] = (f32x4){0.f, 0.f, 0.f, 0.f};
                const bf16x8 wf0 = *(const bf16x8*)&WoS[(nt * 16 + t16) * 72 + 0  + quad * 8];
                const bf16x8 wf1 = *(const bf16x8*)&WoS[(nt * 16 + t16) * 72 + 32 + quad * 8];
                R[nt] = __builtin_amdgcn_mfma_f32_16x16x32_bf16(pf0, wf0, R[nt], 0, 0, 0);
                R[nt] = __builtin_amdgcn_mfma_f32_16x16x32_bf16(pf1, wf1, R[nt], 0, 0, 0);
            }

            const int srow_base = qt * 128 + rs * 64 + w4 * 16 + quad * 4;
#pragma unroll
            for (int rr = 0; rr < 4; rr++) {
                const size_t base = ((size_t)b * SEQ + srow_base + rr) * 64;
#pragma unroll
                for (int nt = 0; nt < 4; nt++)
                    atomicAdd(&out[base + nt * 16 + t16], R[nt][rr]);
            }
        }
    }
}

// ---------------------------------------------------------------------------
extern "C" void kernel_launch(void* const* d_in, const int* in_sizes, int n_in,
                              void* d_out, int out_size, void* d_ws, size_t ws_size,
                              hipStream_t stream)
{
    const float* query = (const float*)d_in[0];
    const float* key_  = (const float*)d_in[1];
    const float* value = (const float*)d_in[2];
    const float* Wq    = (const float*)d_in[3];
    const float* bq    = (const float*)d_in[4];
    const float* Wk    = (const float*)d_in[5];
    const float* bk    = (const float*)d_in[6];
    const float* Wv    = (const float*)d_in[7];
    const float* bv    = (const float*)d_in[8];
    const float* Wo    = (const float*)d_in[9];
    const float* bo    = (const float*)d_in[10];
    // d_in[11..15] dead (softmax shift-invariance)

    float* out = (float*)d_out;
    char* ws   = (char*)d_ws;
    bf16* Qh  = (bf16*)(ws + (size_t) 0 * 1024 * 1024);          // [B,H,S,64]  8 MB
    bf16* Kh  = (bf16*)(ws + (size_t) 8 * 1024 * 1024);          //             8 MB
    bf16* Vt  = (bf16*)(ws + (size_t)16 * 1024 * 1024);          // [B,H,64,S]  8 MB
    bf16* WoT = (bf16*)(ws + (size_t)24 * 1024 * 1024);          // [64,512]   64 KB
    bf16* WqT = (bf16*)(ws + (size_t)24 * 1024 * 1024 + 65536);  // [512,64]   64 KB
    bf16* WkT = (bf16*)(ws + (size_t)24 * 1024 * 1024 + 131072); //            64 KB
    bf16* WvT = (bf16*)(ws + (size_t)24 * 1024 * 1024 + 196608); //            64 KB

    init_kernel<<<dim3(2048), 256, 0, stream>>>(Wq, Wk, Wv, Wo, bo, out,
                                                WqT, WkT, WvT, WoT);
    qkv_mfma_kernel<<<dim3(64, 8, 3), 256, 0, stream>>>(
        query, key_, value, WqT, WkT, WvT, bq, bk, bv, Qh, Kh, Vt);
    flash_attn_kernel<<<dim3(64, 8), 512, 0, stream>>>(Qh, Kh, Vt, WoT, out);
}